// Round 4
// baseline (609.234 us; speedup 1.0000x reference)
//
#include <hip/hip_runtime.h>
#include <math.h>

#define NN 10000
#define NE 160000
#define E2 (NE + NN)
#define NG 20
#define MPAD 10112   // 79 * 128

typedef __attribute__((ext_vector_type(8))) short short8;
typedef __attribute__((ext_vector_type(4))) float f32x4;

// ---------- helpers ----------
__device__ inline unsigned short f2bf(float f){
  unsigned u = __float_as_uint(f);
  unsigned r = u + 0x7FFFu + ((u >> 16) & 1u);
  return (unsigned short)(r >> 16);
}
__device__ inline float bf2f(unsigned short h){ return __uint_as_float(((unsigned)h) << 16); }

__device__ inline void gload_lds16(const void* g, void* l){
  __builtin_amdgcn_global_load_lds((const __attribute__((address_space(1))) void*)g,
                                   (__attribute__((address_space(3))) void*)l, 16, 0, 0);
}

// ---------- graph boundary (batch is sorted) ----------
__global__ void k_gptr(const int* __restrict__ batch, int* __restrict__ gptr){
  int g = threadIdx.x;
  if (g > NG) return;
  int lo = 0, hi = NN;
  while (lo < hi){ int mid = (lo+hi)>>1; if (batch[mid] < g) lo = mid+1; else hi = mid; }
  gptr[g] = lo;
}

// ---------- CSR build (by dst, self-loops appended) ----------
__global__ void k_count(const int* __restrict__ ei, int* __restrict__ cnt){
  int e = blockIdx.x*256 + threadIdx.x;
  if (e >= E2) return;
  int d = (e < NE) ? ei[NE + e] : (e - NE);
  atomicAdd(&cnt[d], 1);
}

__global__ void k_scan(const int* __restrict__ cnt, int* __restrict__ ptr){
  __shared__ int tpre[256];
  __shared__ int tsum[256];
  int tid = threadIdx.x;
  const int per = (NN + 255)/256;
  int base = tid*per;
  int s = 0;
  for (int i=0;i<per;i++){ int idx=base+i; if (idx<NN) s += cnt[idx]; }
  tsum[tid] = s;
  __syncthreads();
  if (tid == 0){
    int run = 0;
    for (int i=0;i<256;i++){ tpre[i]=run; run += tsum[i]; }
    ptr[NN] = run;
  }
  __syncthreads();
  int run = tpre[tid];
  for (int i=0;i<per;i++){ int idx=base+i; if (idx<NN){ ptr[idx]=run; run += cnt[idx]; } }
}

__global__ void k_copy(const int* __restrict__ src, int* __restrict__ dst){
  int i = blockIdx.x*256 + threadIdx.x;
  if (i < NN) dst[i] = src[i];
}

__global__ void k_scatter(const int* __restrict__ ei, int* __restrict__ fill, int* __restrict__ csrc){
  int e = blockIdx.x*256 + threadIdx.x;
  if (e >= E2) return;
  int s, d;
  if (e < NE){ s = ei[e]; d = ei[NE + e]; } else { s = d = e - NE; }
  int pos = atomicAdd(&fill[d], 1);
  csrc[pos] = s;
}

// ---------- conversions ----------
__global__ void k_xconv(const float* __restrict__ x, unsigned short* __restrict__ xbf){
  int i = blockIdx.x*256 + threadIdx.x;
  if (i >= MPAD*64) return;
  int r = i >> 6, c = i & 63;
  float v = (r < NN && c < 50) ? x[r*50 + c] : 0.f;
  xbf[i] = f2bf(v);
}

// W: [K][N] row-major f32 -> Wt: [Npad][Kpad] bf16 (transposed, zero-padded)
__global__ void k_wconv(const float* __restrict__ W, unsigned short* __restrict__ Wt,
                        int K, int N, int Kpad, int Npad){
  int i = blockIdx.x*256 + threadIdx.x;
  if (i >= Npad*Kpad) return;
  int nn = i / Kpad, kk = i - nn*Kpad;
  float v = (nn < N && kk < K) ? W[(size_t)kk*N + nn] : 0.f;
  Wt[i] = f2bf(v);
}

// pad att vectors to FS and zero a_s/a_d accumulators
__global__ void k_attpad(const float* __restrict__ AS, const float* __restrict__ AD,
                         float* __restrict__ asp, float* __restrict__ adp,
                         float* __restrict__ a_s, float* __restrict__ a_d, int F, int FS, int H){
  int i = blockIdx.x*256 + threadIdx.x;
  if (i < FS){ asp[i] = (i < F) ? AS[i] : 0.f; adp[i] = (i < F) ? AD[i] : 0.f; }
  if (i < NN*H){ a_s[i] = 0.f; a_d[i] = 0.f; }
}

// ---------- bf16 MFMA GEMM + fused attention-halves epilogue ----------
// C[M,FS] = A[Mpad,K] x Bt[FS,K]^T ; also a_s/a_d += h . att (f32, atomics)
__global__ __launch_bounds__(256) void k_mfma_gemm(
    const unsigned short* __restrict__ A,   // [MPAD][K] bf16
    const unsigned short* __restrict__ Bt,  // [FS][K] bf16
    unsigned short* __restrict__ Cbf,       // [M][FS] bf16 out
    const float* __restrict__ asp,          // [FS] padded att_src
    const float* __restrict__ adp,          // [FS] padded att_dst
    float* __restrict__ a_s, float* __restrict__ a_d,  // [M*H]
    int M, int K, int FS, int ncb, int C, int H)
{
  __shared__ unsigned short sA[128*32];
  __shared__ unsigned short sB[128*32];
  const int tid = threadIdx.x;
  const int wave = tid >> 6;
  const int lane = tid & 63;
  // bijective XCD swizzle (m204): contiguous wg-chunks per XCD, col-tile fastest
  const int nwg = gridDim.x;
  const int q = nwg >> 3, rmod = nwg & 7;
  const int xcd = blockIdx.x & 7, idx = blockIdx.x >> 3;
  const int wg = (xcd < rmod) ? (xcd*(q+1) + idx) : (rmod*(q+1) + (xcd - rmod)*q + idx);
  const int rowt = wg / ncb;
  const int colt = wg - rowt*ncb;
  const int row0 = rowt * 128;
  const int col0 = colt * 128;
  const int wr = (wave >> 1) * 64;
  const int wc = (wave & 1) * 64;
  f32x4 acc[4][4];
  #pragma unroll
  for (int i=0;i<4;i++)
    #pragma unroll
    for (int j=0;j<4;j++){ acc[i][j][0]=0.f; acc[i][j][1]=0.f; acc[i][j][2]=0.f; acc[i][j][3]=0.f; }

  const unsigned short* aSrc = A + (size_t)(row0 + (tid>>2))*K + (tid&3)*8;
  const unsigned short* bSrc = Bt + (size_t)(col0 + (tid>>2))*K + (tid&3)*8;
  char* ldsA = (char*)sA + wave*1024;
  char* ldsB = (char*)sB + wave*1024;
  const int koff = (lane >> 4) * 8;

  for (int k0 = 0; k0 < K; k0 += 32){
    gload_lds16(aSrc + k0,                  ldsA);
    gload_lds16(aSrc + (size_t)64*K + k0,   ldsA + 4096);
    gload_lds16(bSrc + k0,                  ldsB);
    gload_lds16(bSrc + (size_t)64*K + k0,   ldsB + 4096);
    __syncthreads();
    short8 af[4], bfr[4];
    #pragma unroll
    for (int m=0;m<4;m++)
      af[m] = *(const short8*)(sA + (wr + m*16 + (lane&15))*32 + koff);
    #pragma unroll
    for (int n=0;n<4;n++)
      bfr[n] = *(const short8*)(sB + (wc + n*16 + (lane&15))*32 + koff);
    #pragma unroll
    for (int m=0;m<4;m++)
      #pragma unroll
      for (int n=0;n<4;n++)
        acc[m][n] = __builtin_amdgcn_mfma_f32_16x16x32_bf16(af[m], bfr[n], acc[m][n], 0, 0, 0);
    __syncthreads();
  }
  const int cr = (lane >> 4) * 4;
  const int cc = lane & 15;
  // C store (bf16)
  #pragma unroll
  for (int m=0;m<4;m++){
    #pragma unroll
    for (int n=0;n<4;n++){
      int col = col0 + wc + n*16 + cc;
      #pragma unroll
      for (int r=0;r<4;r++){
        int row = row0 + wr + m*16 + cr + r;
        if (row < M) Cbf[(size_t)row*FS + col] = f2bf(acc[m][n][r]);
      }
    }
  }
  // fused attention halves: per-row partial dots over this wave's 64 cols
  float asv[4], adv[4];
  #pragma unroll
  for (int n=0;n<4;n++){
    int col = col0 + wc + n*16 + cc;
    asv[n] = asp[col]; adv[n] = adp[col];
  }
  const int head = (col0 + wc) / C;
  #pragma unroll
  for (int m=0;m<4;m++){
    #pragma unroll
    for (int r=0;r<4;r++){
      float ss = 0.f, sd = 0.f;
      #pragma unroll
      for (int n=0;n<4;n++){ float v = acc[m][n][r]; ss += v*asv[n]; sd += v*adv[n]; }
      #pragma unroll
      for (int o=8;o;o>>=1){ ss += __shfl_xor(ss, o); sd += __shfl_xor(sd, o); }
      int row = row0 + wr + m*16 + cr + r;
      if (cc == 0 && row < M){
        atomicAdd(&a_s[row*H + head], ss);
        atomicAdd(&a_d[row*H + head], sd);
      }
    }
  }
}

// ---------- per-node softmax -> alphaT[h][E2] (one wave per node) ----------
__global__ void k_alpha(const float* __restrict__ a_s, const float* __restrict__ a_d,
                        const int* __restrict__ ptr, const int* __restrict__ csrc,
                        float* __restrict__ alphaT, int H, int LH){
  int node = blockIdx.x;
  int lane = threadIdx.x;   // 64
  int beg = ptr[node], deg = ptr[node+1] - beg;
  int items = deg << LH;    // deg*H
  int hh = lane & (H-1);    // constant per lane (64 % H == 0)
  float ad = a_d[node*H + hh];
  float mx = -INFINITY;
  for (int i = lane; i < items; i += 64){
    int e = i >> LH;
    int s = csrc[beg + e];
    float ev = a_s[s*H + hh] + ad;
    ev = ev > 0.f ? ev : 0.2f*ev;
    mx = fmaxf(mx, ev);
  }
  for (int o = H; o < 64; o <<= 1) mx = fmaxf(mx, __shfl_xor(mx, o));
  float den = 0.f;
  for (int i = lane; i < items; i += 64){
    int e = i >> LH;
    int s = csrc[beg + e];
    float ev = a_s[s*H + hh] + ad;
    ev = ev > 0.f ? ev : 0.2f*ev;
    den += __expf(ev - mx);
  }
  for (int o = H; o < 64; o <<= 1) den += __shfl_xor(den, o);
  float inv = 1.f / (den + 1e-16f);
  for (int i = lane; i < items; i += 64){
    int e = i >> LH;
    int s = csrc[beg + e];
    float ev = a_s[s*H + hh] + ad;
    ev = ev > 0.f ? ev : 0.2f*ev;
    alphaT[(size_t)hh*E2 + beg + e] = __expf(ev - mx) * inv;
  }
}

// ---------- weighted gather: grid (NN, H); block covers CS = L*8 channels ----------
template<int L>
__global__ __launch_bounds__(256) void k_gather2(
    const unsigned short* __restrict__ h, int FS,
    const float* __restrict__ alphaT,
    const int* __restrict__ ptr, const int* __restrict__ csrc,
    const float* __restrict__ bias, float* __restrict__ out,
    int F, int C, int outF)
{
  constexpr int NGRP = 256 / L;
  constexpr int CS = L * 8;
  const int node = blockIdx.x;
  const int head = blockIdx.y;
  const int colbase = head * C;
  const int beg = ptr[node], deg = ptr[node+1] - beg;
  __shared__ int ssrc[256];
  __shared__ float sal[256];
  __shared__ float red[NGRP * CS];   // 8 KB
  const int tid = threadIdx.x;
  const int grp = tid / L, li = tid % L;
  const int c0 = colbase + li*8;
  const float* aT = alphaT + (size_t)head*E2 + beg;
  float acc[8] = {0.f,0.f,0.f,0.f,0.f,0.f,0.f,0.f};
  for (int b0 = 0; b0 < deg; b0 += 256){
    int bn = min(256, deg - b0);
    if (tid < bn){ ssrc[tid] = csrc[beg + b0 + tid]; sal[tid] = aT[b0 + tid]; }
    __syncthreads();
    for (int e = grp; e < bn; e += NGRP){
      int s = ssrc[e];
      float al = sal[e];
      short8 v = *(const short8*)(h + (size_t)s*FS + c0);
      #pragma unroll
      for (int j=0;j<8;j++) acc[j] += bf2f((unsigned short)v[j]) * al;
    }
    __syncthreads();
  }
  #pragma unroll
  for (int j=0;j<8;j++) red[grp*CS + li*8 + j] = acc[j];
  __syncthreads();
  for (int c = tid; c < CS; c += 256){
    float s = 0.f;
    #pragma unroll
    for (int g=0; g<NGRP; g++) s += red[g*CS + c];
    int oc = colbase + c;
    if (oc < F) out[(size_t)node*outF + oc] = s + bias[oc];
  }
}

// ---------- GraphNorm stats / coefs / apply+ELU ----------
#define NSPLIT 16
__global__ void k_gnstats(const float* __restrict__ x, const int* __restrict__ gptr,
                          float* __restrict__ gsum, float* __restrict__ gsq, int F){
  int g = blockIdx.x, cc = blockIdx.y, sp = blockIdx.z;
  int c = cc*256 + threadIdx.x;
  if (c >= F) return;
  int beg = gptr[g], end = gptr[g+1];
  int n = end - beg;
  int per = (n + NSPLIT - 1) / NSPLIT;
  int nb = beg + sp*per, ne = min(end, nb + per);
  if (ne <= nb) return;
  float s = 0.f, q = 0.f;
  for (int i = nb; i < ne; i++){ float v = x[(size_t)i*F + c]; s += v; q += v*v; }
  atomicAdd(&gsum[g*F + c], s);
  atomicAdd(&gsq[g*F + c], q);
}

__global__ void k_coef(const float* __restrict__ gsum, const float* __restrict__ gsq, const int* __restrict__ gptr,
                       const float* __restrict__ w, const float* __restrict__ b, const float* __restrict__ ms,
                       float* __restrict__ cA, float* __restrict__ cB, int F){
  int i = blockIdx.x*256 + threadIdx.x;
  if (i >= NG*F) return;
  int g = i / F, c = i - g*F;
  float cntf = (float)(gptr[g+1] - gptr[g]);
  float m = gsum[i] / cntf;
  float s = ms[c];
  float ex2 = gsq[i] / cntf;
  float var = ex2 - 2.f*s*m*m + s*s*m*m;
  float inv = rsqrtf(var + 1e-5f);
  float wa = w[c]*inv;
  cA[i] = wa;
  cB[i] = b[c] - wa*m*s;
}

__global__ void k_applyelu(const float* __restrict__ x, const int* __restrict__ batch,
                           const float* __restrict__ cA, const float* __restrict__ cB,
                           unsigned short* __restrict__ obf, int F){
  size_t i = (size_t)blockIdx.x*256 + threadIdx.x;
  if (i >= (size_t)NN*F) return;
  int node = (int)(i / F);
  int c = (int)(i - (size_t)node*F);
  int g = batch[node];
  float y = cA[g*F + c]*x[i] + cB[g*F + c];
  y = y > 0.f ? y : expm1f(y);
  obf[i] = f2bf(y);
}

// ---------- orchestration ----------
extern "C" void kernel_launch(void* const* d_in, const int* in_sizes, int n_in,
                              void* d_out, int out_size, void* d_ws, size_t ws_size,
                              hipStream_t stream){
  (void)in_sizes; (void)n_in; (void)out_size; (void)ws_size;
  const float* x     = (const float*)d_in[0];
  const int*   ei    = (const int*)d_in[1];
  const int*   batch = (const int*)d_in[2];
  const float* W[4]  = {(const float*)d_in[3],  (const float*)d_in[7],  (const float*)d_in[11], (const float*)d_in[15]};
  const float* AS[4] = {(const float*)d_in[4],  (const float*)d_in[8],  (const float*)d_in[12], (const float*)d_in[16]};
  const float* AD[4] = {(const float*)d_in[5],  (const float*)d_in[9],  (const float*)d_in[13], (const float*)d_in[17]};
  const float* BI[4] = {(const float*)d_in[6],  (const float*)d_in[10], (const float*)d_in[14], (const float*)d_in[18]};
  const float* GW[3] = {(const float*)d_in[19], (const float*)d_in[22], (const float*)d_in[25]};
  const float* GB[3] = {(const float*)d_in[20], (const float*)d_in[23], (const float*)d_in[26]};
  const float* GA[3] = {(const float*)d_in[21], (const float*)d_in[24], (const float*)d_in[27]};

  float* ws   = (float*)d_ws;
  float* bufB = ws;                                  // [NN,1024] f32 (gather out / gnorm)
  float* a_s  = bufB + (size_t)NN*1024;              // [NN,4]
  float* a_d  = a_s + (size_t)NN*4;                  // [NN,4]
  float* gsum = a_d + (size_t)NN*4;                  // [NG,1024]
  float* gsq  = gsum + (size_t)NG*1024;              // [NG,1024]
  float* cA   = gsq  + (size_t)NG*1024;              // [NG,1024]
  float* cB   = cA   + (size_t)NG*1024;              // [NG,1024]
  float* asp  = cB   + (size_t)NG*1024;              // [1024]
  float* adp  = asp + 1024;                          // [1024]
  float* alphaT = adp + 1024;                        // [4][E2]
  int* ptr  = (int*)(alphaT + (size_t)4*E2);         // [NN+1]
  int* fill = ptr + (NN + 8);                        // [NN+1]
  int* csrc = fill + (NN + 8);                       // [E2]
  int* gptr = csrc + E2;                             // [NG+1] (pad to 24)
  unsigned short* xbf = (unsigned short*)(gptr + 24);// [MPAD,64] bf16
  unsigned short* abf = xbf + (size_t)MPAD*64;       // [MPAD,1024] bf16 (layer inputs 1-3)
  unsigned short* hbf = abf + (size_t)MPAD*1024;     // [NN,1024] bf16 (GEMM out)
  unsigned short* Wt  = hbf + (size_t)NN*1024;       // [1024,1024] bf16 (per-layer W^T)

  // ---- CSR + graph boundaries (once per call) ----
  hipMemsetAsync(fill, 0, sizeof(int)*(NN+1), stream);
  k_gptr<<<1, 32, 0, stream>>>(batch, gptr);
  k_count<<<(E2+255)/256, 256, 0, stream>>>(ei, fill);
  k_scan<<<1, 256, 0, stream>>>(fill, ptr);
  k_copy<<<(NN+255)/256, 256, 0, stream>>>(ptr, fill);
  k_scatter<<<(E2+255)/256, 256, 0, stream>>>(ei, fill, csrc);
  k_xconv<<<(MPAD*64+255)/256, 256, 0, stream>>>(x, xbf);

  const int Kp[4]  = {64, 1024, 1024, 1024};
  const int Kr[4]  = {50, 1024, 1024, 1024};
  const int Np[4]  = {1024, 1024, 1024, 128};
  for (int li = 0; li < 4; ++li){
    int H = (li == 3) ? 1 : 4;
    int LH = (li == 3) ? 0 : 2;
    int C = (li == 3) ? 121 : 256;
    int F = H*C;
    int FS = Np[li];                       // padded h stride (1024 / 128)
    const unsigned short* Ain = (li == 0) ? xbf : abf;
    k_wconv<<<(Np[li]*Kp[li]+255)/256, 256, 0, stream>>>(W[li], Wt, Kr[li], F, Kp[li], Np[li]);
    k_attpad<<<160, 256, 0, stream>>>(AS[li], AD[li], asp, adp, a_s, a_d, F, FS, H);
    int ncb = Np[li]/128;
    int nwg = (MPAD/128) * ncb;
    k_mfma_gemm<<<nwg, 256, 0, stream>>>(Ain, Wt, hbf, asp, adp, a_s, a_d, NN, Kp[li], FS, ncb, C, H);
    k_alpha<<<NN, 64, 0, stream>>>(a_s, a_d, ptr, csrc, alphaT, H, LH);
    float* gout = (li == 3) ? (float*)d_out : bufB;
    if (li < 3)
      k_gather2<32><<<dim3(NN, 4), 256, 0, stream>>>(hbf, FS, alphaT, ptr, csrc, BI[li], gout, F, C, F);
    else
      k_gather2<16><<<dim3(NN, 1), 256, 0, stream>>>(hbf, FS, alphaT, ptr, csrc, BI[li], gout, F, C, F);
    if (li < 3){
      hipMemsetAsync(gsum, 0, sizeof(float)*2*NG*1024, stream);
      k_gnstats<<<dim3(NG, (F+255)/256, NSPLIT), 256, 0, stream>>>(bufB, gptr, gsum, gsq, F);
      k_coef<<<(NG*F + 255)/256, 256, 0, stream>>>(gsum, gsq, gptr, GW[li], GB[li], GA[li], cA, cB, F);
      size_t tot = (size_t)NN*F;
      k_applyelu<<<(unsigned)((tot + 255)/256), 256, 0, stream>>>(bufB, batch, cA, cB, abf, F);
    }
  }
}

// Round 5
// 574.134 us; speedup vs baseline: 1.0611x; 1.0611x over previous
//
#include <hip/hip_runtime.h>
#include <math.h>

#define NN 10000
#define NE 160000
#define E2 (NE + NN)
#define NG 20
#define MPAD 10112   // 158 * 64

typedef __attribute__((ext_vector_type(8))) short short8;
typedef __attribute__((ext_vector_type(4))) float f32x4;

// ---------- helpers ----------
__device__ inline unsigned short f2bf(float f){
  unsigned u = __float_as_uint(f);
  unsigned r = u + 0x7FFFu + ((u >> 16) & 1u);
  return (unsigned short)(r >> 16);
}
__device__ inline float bf2f(unsigned short h){ return __uint_as_float(((unsigned)h) << 16); }

__device__ inline void gload_lds16(const void* g, void* l){
  __builtin_amdgcn_global_load_lds((const __attribute__((address_space(1))) void*)g,
                                   (__attribute__((address_space(3))) void*)l, 16, 0, 0);
}

// ---------- graph boundary (batch is sorted) ----------
__global__ void k_gptr(const int* __restrict__ batch, int* __restrict__ gptr){
  int g = threadIdx.x;
  if (g > NG) return;
  int lo = 0, hi = NN;
  while (lo < hi){ int mid = (lo+hi)>>1; if (batch[mid] < g) lo = mid+1; else hi = mid; }
  gptr[g] = lo;
}

// ---------- CSR build (by dst, self-loops appended) ----------
__global__ void k_count(const int* __restrict__ ei, int* __restrict__ cnt){
  int e = blockIdx.x*256 + threadIdx.x;
  if (e >= E2) return;
  int d = (e < NE) ? ei[NE + e] : (e - NE);
  atomicAdd(&cnt[d], 1);
}

__global__ void k_scan(const int* __restrict__ cnt, int* __restrict__ ptr){
  __shared__ int tpre[256];
  __shared__ int tsum[256];
  int tid = threadIdx.x;
  const int per = (NN + 255)/256;
  int base = tid*per;
  int s = 0;
  for (int i=0;i<per;i++){ int idx=base+i; if (idx<NN) s += cnt[idx]; }
  tsum[tid] = s;
  __syncthreads();
  if (tid == 0){
    int run = 0;
    for (int i=0;i<256;i++){ tpre[i]=run; run += tsum[i]; }
    ptr[NN] = run;
  }
  __syncthreads();
  int run = tpre[tid];
  for (int i=0;i<per;i++){ int idx=base+i; if (idx<NN){ ptr[idx]=run; run += cnt[idx]; } }
}

__global__ void k_copy(const int* __restrict__ src, int* __restrict__ dst){
  int i = blockIdx.x*256 + threadIdx.x;
  if (i < NN) dst[i] = src[i];
}

__global__ void k_scatter(const int* __restrict__ ei, int* __restrict__ fill, int* __restrict__ csrc){
  int e = blockIdx.x*256 + threadIdx.x;
  if (e >= E2) return;
  int s, d;
  if (e < NE){ s = ei[e]; d = ei[NE + e]; } else { s = d = e - NE; }
  int pos = atomicAdd(&fill[d], 1);
  csrc[pos] = s;
}

// ---------- conversions ----------
__global__ void k_xconv(const float* __restrict__ x, unsigned short* __restrict__ xbf){
  int i = blockIdx.x*256 + threadIdx.x;
  if (i >= MPAD*64) return;
  int r = i >> 6, c = i & 63;
  float v = (r < NN && c < 50) ? x[r*50 + c] : 0.f;
  xbf[i] = f2bf(v);
}

// W: [K][N] row-major f32 -> Wt: [Npad][Kpad] bf16 (transposed, zero-padded)
__global__ void k_wconv(const float* __restrict__ W, unsigned short* __restrict__ Wt,
                        int K, int N, int Kpad, int Npad){
  int i = blockIdx.x*256 + threadIdx.x;
  if (i >= Npad*Kpad) return;
  int nn = i / Kpad, kk = i - nn*Kpad;
  float v = (nn < N && kk < K) ? W[(size_t)kk*N + nn] : 0.f;
  Wt[i] = f2bf(v);
}

// ---------- bf16 MFMA GEMM: C[M,FS] = A[Mpad,K] x Bt[FS,K]^T ----------
// TBM x TBN tile, BK=32, 4 waves (2x2), XCD-swizzled col-fastest grid.
template<int TBM, int TBN>
__global__ __launch_bounds__(256) void k_mfma_gemm(
    const unsigned short* __restrict__ A,   // [MPAD][K] bf16
    const unsigned short* __restrict__ Bt,  // [FS][K] bf16
    unsigned short* __restrict__ Cbf,       // [M][FS] bf16 out
    int M, int K, int FS, int ncb)
{
  constexpr int MFR = TBM/32;   // 16x16 frags per wave in M (wave covers TBM/2 rows)
  constexpr int NFR = TBN/32;
  __shared__ unsigned short sA[TBM*32];
  __shared__ unsigned short sB[TBN*32];
  const int tid = threadIdx.x;
  const int wave = tid >> 6;
  const int lane = tid & 63;
  // bijective XCD swizzle (m204): contiguous wg-chunks per XCD
  const int nwg = gridDim.x;
  const int q = nwg >> 3, rmod = nwg & 7;
  const int xcd = blockIdx.x & 7, idx = blockIdx.x >> 3;
  const int wg = (xcd < rmod) ? (xcd*(q+1) + idx) : (rmod*(q+1) + (xcd - rmod)*q + idx);
  const int rowt = wg / ncb;
  const int colt = wg - rowt*ncb;
  const int row0 = rowt * TBM;
  const int col0 = colt * TBN;
  const int wr = (wave >> 1) * (TBM/2);
  const int wc = (wave & 1) * (TBN/2);
  f32x4 acc[MFR][NFR];
  #pragma unroll
  for (int i=0;i<MFR;i++)
    #pragma unroll
    for (int j=0;j<NFR;j++){ acc[i][j][0]=0.f; acc[i][j][1]=0.f; acc[i][j][2]=0.f; acc[i][j][3]=0.f; }

  const unsigned short* aSrc = A + (size_t)(row0 + (tid>>2))*K + (tid&3)*8;
  const unsigned short* bSrc = Bt + (size_t)(col0 + (tid>>2))*K + (tid&3)*8;
  char* ldsA = (char*)sA + wave*1024;
  char* ldsB = (char*)sB + wave*1024;
  const int koff = (lane >> 4) * 8;

  for (int k0 = 0; k0 < K; k0 += 32){
    #pragma unroll
    for (int hh=0; hh<TBM/64; hh++) gload_lds16(aSrc + (size_t)hh*64*K + k0, ldsA + hh*4096);
    #pragma unroll
    for (int hh=0; hh<TBN/64; hh++) gload_lds16(bSrc + (size_t)hh*64*K + k0, ldsB + hh*4096);
    __syncthreads();
    short8 af[MFR], bfr[NFR];
    #pragma unroll
    for (int m=0;m<MFR;m++)
      af[m] = *(const short8*)(sA + (wr + m*16 + (lane&15))*32 + koff);
    #pragma unroll
    for (int n=0;n<NFR;n++)
      bfr[n] = *(const short8*)(sB + (wc + n*16 + (lane&15))*32 + koff);
    #pragma unroll
    for (int m=0;m<MFR;m++)
      #pragma unroll
      for (int n=0;n<NFR;n++)
        acc[m][n] = __builtin_amdgcn_mfma_f32_16x16x32_bf16(af[m], bfr[n], acc[m][n], 0, 0, 0);
    __syncthreads();
  }
  const int cr = (lane >> 4) * 4;
  const int cc = lane & 15;
  #pragma unroll
  for (int m=0;m<MFR;m++){
    #pragma unroll
    for (int n=0;n<NFR;n++){
      int col = col0 + wc + n*16 + cc;
      #pragma unroll
      for (int r=0;r<4;r++){
        int row = row0 + wr + m*16 + cr + r;
        if (row < M) Cbf[(size_t)row*FS + col] = f2bf(acc[m][n][r]);
      }
    }
  }
}

// ---------- per-node per-head attention halves (bf16 h, stride FS) ----------
__global__ void k_attprep(const unsigned short* __restrict__ h, const float* __restrict__ atts,
                          const float* __restrict__ attd,
                          float* __restrict__ a_s, float* __restrict__ a_d, int H, int C, int FS){
  int node = blockIdx.x, head = blockIdx.y;
  int lane = threadIdx.x;           // 64
  const unsigned short* hp = h + (size_t)node*FS + head*C;
  const float* sp = atts + head*C;
  const float* dp = attd + head*C;
  float ss = 0.f, sd = 0.f;
  for (int c = lane; c < C; c += 64){ float v = bf2f(hp[c]); ss += v*sp[c]; sd += v*dp[c]; }
  #pragma unroll
  for (int o = 32; o; o >>= 1){ ss += __shfl_down(ss, o); sd += __shfl_down(sd, o); }
  if (lane == 0){ a_s[node*H + head] = ss; a_d[node*H + head] = sd; }
}

// ---------- per-node softmax -> alphaT[h][E2] (one wave per node) ----------
__global__ void k_alpha(const float* __restrict__ a_s, const float* __restrict__ a_d,
                        const int* __restrict__ ptr, const int* __restrict__ csrc,
                        float* __restrict__ alphaT, int H, int LH){
  int node = blockIdx.x;
  int lane = threadIdx.x;   // 64
  int beg = ptr[node], deg = ptr[node+1] - beg;
  int items = deg << LH;    // deg*H
  int hh = lane & (H-1);    // constant per lane (64 % H == 0)
  float ad = a_d[node*H + hh];
  float mx = -INFINITY;
  for (int i = lane; i < items; i += 64){
    int e = i >> LH;
    int s = csrc[beg + e];
    float ev = a_s[s*H + hh] + ad;
    ev = ev > 0.f ? ev : 0.2f*ev;
    mx = fmaxf(mx, ev);
  }
  for (int o = H; o < 64; o <<= 1) mx = fmaxf(mx, __shfl_xor(mx, o));
  float den = 0.f;
  for (int i = lane; i < items; i += 64){
    int e = i >> LH;
    int s = csrc[beg + e];
    float ev = a_s[s*H + hh] + ad;
    ev = ev > 0.f ? ev : 0.2f*ev;
    den += __expf(ev - mx);
  }
  for (int o = H; o < 64; o <<= 1) den += __shfl_xor(den, o);
  float inv = 1.f / (den + 1e-16f);
  for (int i = lane; i < items; i += 64){
    int e = i >> LH;
    int s = csrc[beg + e];
    float ev = a_s[s*H + hh] + ad;
    ev = ev > 0.f ? ev : 0.2f*ev;
    alphaT[(size_t)hh*E2 + beg + e] = __expf(ev - mx) * inv;
  }
}

// ---------- weighted gather: grid (NN, H); block covers CS = L*8 channels ----------
template<int L>
__global__ __launch_bounds__(256) void k_gather2(
    const unsigned short* __restrict__ h, int FS,
    const float* __restrict__ alphaT,
    const int* __restrict__ ptr, const int* __restrict__ csrc,
    const float* __restrict__ bias, float* __restrict__ out,
    int F, int C, int outF)
{
  constexpr int NGRP = 256 / L;
  constexpr int CS = L * 8;
  const int node = blockIdx.x;
  const int head = blockIdx.y;
  const int colbase = head * C;
  const int beg = ptr[node], deg = ptr[node+1] - beg;
  __shared__ int ssrc[256];
  __shared__ float sal[256];
  __shared__ float red[NGRP * CS];   // 8 KB
  const int tid = threadIdx.x;
  const int grp = tid / L, li = tid % L;
  const int c0 = colbase + li*8;
  const float* aT = alphaT + (size_t)head*E2 + beg;
  float acc[8] = {0.f,0.f,0.f,0.f,0.f,0.f,0.f,0.f};
  for (int b0 = 0; b0 < deg; b0 += 256){
    int bn = min(256, deg - b0);
    if (tid < bn){ ssrc[tid] = csrc[beg + b0 + tid]; sal[tid] = aT[b0 + tid]; }
    __syncthreads();
    for (int e = grp; e < bn; e += NGRP){
      int s = ssrc[e];
      float al = sal[e];
      short8 v = *(const short8*)(h + (size_t)s*FS + c0);
      #pragma unroll
      for (int j=0;j<8;j++) acc[j] += bf2f((unsigned short)v[j]) * al;
    }
    __syncthreads();
  }
  #pragma unroll
  for (int j=0;j<8;j++) red[grp*CS + li*8 + j] = acc[j];
  __syncthreads();
  for (int c = tid; c < CS; c += 256){
    float s = 0.f;
    #pragma unroll
    for (int g=0; g<NGRP; g++) s += red[g*CS + c];
    int oc = colbase + c;
    if (oc < F) out[(size_t)node*outF + oc] = s + bias[oc];
  }
}

// ---------- GraphNorm stats / coefs / apply+ELU ----------
#define NSPLIT 16
__global__ void k_gnstats(const float* __restrict__ x, const int* __restrict__ gptr,
                          float* __restrict__ gsum, float* __restrict__ gsq, int F){
  int g = blockIdx.x, cc = blockIdx.y, sp = blockIdx.z;
  int c = cc*256 + threadIdx.x;
  if (c >= F) return;
  int beg = gptr[g], end = gptr[g+1];
  int n = end - beg;
  int per = (n + NSPLIT - 1) / NSPLIT;
  int nb = beg + sp*per, ne = min(end, nb + per);
  if (ne <= nb) return;
  float s = 0.f, q = 0.f;
  for (int i = nb; i < ne; i++){ float v = x[(size_t)i*F + c]; s += v; q += v*v; }
  atomicAdd(&gsum[g*F + c], s);
  atomicAdd(&gsq[g*F + c], q);
}

__global__ void k_coef(const float* __restrict__ gsum, const float* __restrict__ gsq, const int* __restrict__ gptr,
                       const float* __restrict__ w, const float* __restrict__ b, const float* __restrict__ ms,
                       float* __restrict__ cA, float* __restrict__ cB, int F){
  int i = blockIdx.x*256 + threadIdx.x;
  if (i >= NG*F) return;
  int g = i / F, c = i - g*F;
  float cntf = (float)(gptr[g+1] - gptr[g]);
  float m = gsum[i] / cntf;
  float s = ms[c];
  float ex2 = gsq[i] / cntf;
  float var = ex2 - 2.f*s*m*m + s*s*m*m;
  float inv = rsqrtf(var + 1e-5f);
  float wa = w[c]*inv;
  cA[i] = wa;
  cB[i] = b[c] - wa*m*s;
}

__global__ void k_applyelu(const float* __restrict__ x, const int* __restrict__ batch,
                           const float* __restrict__ cA, const float* __restrict__ cB,
                           unsigned short* __restrict__ obf, int F){
  size_t i = (size_t)blockIdx.x*256 + threadIdx.x;
  if (i >= (size_t)NN*F) return;
  int node = (int)(i / F);
  int c = (int)(i - (size_t)node*F);
  int g = batch[node];
  float y = cA[g*F + c]*x[i] + cB[g*F + c];
  y = y > 0.f ? y : expm1f(y);
  obf[i] = f2bf(y);
}

// ---------- orchestration ----------
extern "C" void kernel_launch(void* const* d_in, const int* in_sizes, int n_in,
                              void* d_out, int out_size, void* d_ws, size_t ws_size,
                              hipStream_t stream){
  (void)in_sizes; (void)n_in; (void)out_size; (void)ws_size;
  const float* x     = (const float*)d_in[0];
  const int*   ei    = (const int*)d_in[1];
  const int*   batch = (const int*)d_in[2];
  const float* W[4]  = {(const float*)d_in[3],  (const float*)d_in[7],  (const float*)d_in[11], (const float*)d_in[15]};
  const float* AS[4] = {(const float*)d_in[4],  (const float*)d_in[8],  (const float*)d_in[12], (const float*)d_in[16]};
  const float* AD[4] = {(const float*)d_in[5],  (const float*)d_in[9],  (const float*)d_in[13], (const float*)d_in[17]};
  const float* BI[4] = {(const float*)d_in[6],  (const float*)d_in[10], (const float*)d_in[14], (const float*)d_in[18]};
  const float* GW[3] = {(const float*)d_in[19], (const float*)d_in[22], (const float*)d_in[25]};
  const float* GB[3] = {(const float*)d_in[20], (const float*)d_in[23], (const float*)d_in[26]};
  const float* GA[3] = {(const float*)d_in[21], (const float*)d_in[24], (const float*)d_in[27]};

  float* ws   = (float*)d_ws;
  float* bufB = ws;                                  // [NN,1024] f32 (gather out / gnorm)
  float* a_s  = bufB + (size_t)NN*1024;              // [NN,4]
  float* a_d  = a_s + (size_t)NN*4;                  // [NN,4]
  float* gsum = a_d + (size_t)NN*4;                  // [NG,1024]
  float* gsq  = gsum + (size_t)NG*1024;              // [NG,1024]
  float* cA   = gsq  + (size_t)NG*1024;              // [NG,1024]
  float* cB   = cA   + (size_t)NG*1024;              // [NG,1024]
  float* alphaT = cB + (size_t)NG*1024;              // [4][E2]
  int* ptr  = (int*)(alphaT + (size_t)4*E2);         // [NN+1]
  int* fill = ptr + (NN + 8);                        // [NN+1]
  int* csrc = fill + (NN + 8);                       // [E2]
  int* gptr = csrc + E2;                             // [NG+1] (pad to 24)
  unsigned short* xbf = (unsigned short*)(gptr + 24);// [MPAD,64] bf16
  unsigned short* abf = xbf + (size_t)MPAD*64;       // [MPAD,1024] bf16 (layer inputs 1-3)
  unsigned short* hbf = abf + (size_t)MPAD*1024;     // [NN,1024] bf16 (GEMM out)
  unsigned short* Wt  = hbf + (size_t)NN*1024;       // [1024,1024] bf16 (per-layer W^T)

  // ---- CSR + graph boundaries (once per call) ----
  hipMemsetAsync(fill, 0, sizeof(int)*(NN+1), stream);
  k_gptr<<<1, 32, 0, stream>>>(batch, gptr);
  k_count<<<(E2+255)/256, 256, 0, stream>>>(ei, fill);
  k_scan<<<1, 256, 0, stream>>>(fill, ptr);
  k_copy<<<(NN+255)/256, 256, 0, stream>>>(ptr, fill);
  k_scatter<<<(E2+255)/256, 256, 0, stream>>>(ei, fill, csrc);
  k_xconv<<<(MPAD*64+255)/256, 256, 0, stream>>>(x, xbf);

  const int Kp[4]  = {64, 1024, 1024, 1024};
  const int Kr[4]  = {50, 1024, 1024, 1024};
  const int Np[4]  = {1024, 1024, 1024, 128};
  for (int li = 0; li < 4; ++li){
    int H = (li == 3) ? 1 : 4;
    int LH = (li == 3) ? 0 : 2;
    int C = (li == 3) ? 121 : 256;
    int F = H*C;
    int FS = Np[li];                       // padded h stride (1024 / 128)
    const unsigned short* Ain = (li == 0) ? xbf : abf;
    k_wconv<<<(Np[li]*Kp[li]+255)/256, 256, 0, stream>>>(W[li], Wt, Kr[li], F, Kp[li], Np[li]);
    if (li < 3){
      int ncb = Np[li]/128;                // 8
      int nwg = (MPAD/64) * ncb;           // 158*8 = 1264
      k_mfma_gemm<64,128><<<nwg, 256, 0, stream>>>(Ain, Wt, hbf, NN, Kp[li], FS, ncb);
    } else {
      int ncb = Np[li]/64;                 // 2
      int nwg = (MPAD/64) * ncb;           // 316
      k_mfma_gemm<64,64><<<nwg, 256, 0, stream>>>(Ain, Wt, hbf, NN, Kp[li], FS, ncb);
    }
    k_attprep<<<dim3(NN, H), 64, 0, stream>>>(hbf, AS[li], AD[li], a_s, a_d, H, C, FS);
    k_alpha<<<NN, 64, 0, stream>>>(a_s, a_d, ptr, csrc, alphaT, H, LH);
    float* gout = (li == 3) ? (float*)d_out : bufB;
    if (li < 3)
      k_gather2<32><<<dim3(NN, 4), 256, 0, stream>>>(hbf, FS, alphaT, ptr, csrc, BI[li], gout, F, C, F);
    else
      k_gather2<16><<<dim3(NN, 1), 256, 0, stream>>>(hbf, FS, alphaT, ptr, csrc, BI[li], gout, F, C, F);
    if (li < 3){
      hipMemsetAsync(gsum, 0, sizeof(float)*2*NG*1024, stream);
      k_gnstats<<<dim3(NG, (F+255)/256, NSPLIT), 256, 0, stream>>>(bufB, gptr, gsum, gsq, F);
      k_coef<<<(NG*F + 255)/256, 256, 0, stream>>>(gsum, gsq, gptr, GW[li], GB[li], GA[li], cA, cB, F);
      size_t tot = (size_t)NN*F;
      k_applyelu<<<(unsigned)((tot + 255)/256), 256, 0, stream>>>(bufB, batch, cA, cB, abf, F);
    }
  }
}

// Round 6
// 570.026 us; speedup vs baseline: 1.0688x; 1.0072x over previous
//
#include <hip/hip_runtime.h>
#include <math.h>

#define NN 10000
#define NE 160000
#define E2 (NE + NN)
#define NG 20
#define MPAD 10112   // 158 * 64

typedef __attribute__((ext_vector_type(8))) short short8;
typedef __attribute__((ext_vector_type(4))) float f32x4;

// ---------- helpers ----------
__device__ inline unsigned short f2bf(float f){
  unsigned u = __float_as_uint(f);
  unsigned r = u + 0x7FFFu + ((u >> 16) & 1u);
  return (unsigned short)(r >> 16);
}
__device__ inline float bf2f(unsigned short h){ return __uint_as_float(((unsigned)h) << 16); }

__device__ inline void gload_lds16(const void* g, void* l){
  __builtin_amdgcn_global_load_lds((const __attribute__((address_space(1))) void*)g,
                                   (__attribute__((address_space(3))) void*)l, 16, 0, 0);
}

// ---------- graph boundary (batch is sorted) ----------
__global__ void k_gptr(const int* __restrict__ batch, int* __restrict__ gptr){
  int g = threadIdx.x;
  if (g > NG) return;
  int lo = 0, hi = NN;
  while (lo < hi){ int mid = (lo+hi)>>1; if (batch[mid] < g) lo = mid+1; else hi = mid; }
  gptr[g] = lo;
}

// ---------- CSR build (by dst, self-loops appended) ----------
__global__ void k_count(const int* __restrict__ ei, int* __restrict__ cnt){
  int e = blockIdx.x*256 + threadIdx.x;
  if (e >= E2) return;
  int d = (e < NE) ? ei[NE + e] : (e - NE);
  atomicAdd(&cnt[d], 1);
}

__global__ void k_scan(const int* __restrict__ cnt, int* __restrict__ ptr){
  __shared__ int tpre[256];
  __shared__ int tsum[256];
  int tid = threadIdx.x;
  const int per = (NN + 255)/256;
  int base = tid*per;
  int s = 0;
  for (int i=0;i<per;i++){ int idx=base+i; if (idx<NN) s += cnt[idx]; }
  tsum[tid] = s;
  __syncthreads();
  if (tid == 0){
    int run = 0;
    for (int i=0;i<256;i++){ tpre[i]=run; run += tsum[i]; }
    ptr[NN] = run;
  }
  __syncthreads();
  int run = tpre[tid];
  for (int i=0;i<per;i++){ int idx=base+i; if (idx<NN){ ptr[idx]=run; run += cnt[idx]; } }
}

__global__ void k_copy(const int* __restrict__ src, int* __restrict__ dst){
  int i = blockIdx.x*256 + threadIdx.x;
  if (i < NN) dst[i] = src[i];
}

__global__ void k_scatter(const int* __restrict__ ei, int* __restrict__ fill, int* __restrict__ csrc){
  int e = blockIdx.x*256 + threadIdx.x;
  if (e >= E2) return;
  int s, d;
  if (e < NE){ s = ei[e]; d = ei[NE + e]; } else { s = d = e - NE; }
  int pos = atomicAdd(&fill[d], 1);
  csrc[pos] = s;
}

// ---------- conversions ----------
__global__ void k_xconv(const float* __restrict__ x, unsigned short* __restrict__ xbf){
  int i = blockIdx.x*256 + threadIdx.x;
  if (i >= MPAD*64) return;
  int r = i >> 6, c = i & 63;
  float v = (r < NN && c < 50) ? x[r*50 + c] : 0.f;
  xbf[i] = f2bf(v);
}

// W: [K][N] row-major f32 -> Wt: [Npad][Kpad] bf16 (transposed, zero-padded)
__global__ void k_wconv(const float* __restrict__ W, unsigned short* __restrict__ Wt,
                        int K, int N, int Kpad, int Npad){
  int i = blockIdx.x*256 + threadIdx.x;
  if (i >= Npad*Kpad) return;
  int nn = i / Kpad, kk = i - nn*Kpad;
  float v = (nn < N && kk < K) ? W[(size_t)kk*N + nn] : 0.f;
  Wt[i] = f2bf(v);
}

// ---------- bf16 MFMA GEMM: C[M,FS] = A[Mpad,K] x Bt[FS,K]^T ----------
// TBM x TBN tile, BK=32, 4 waves (2x2), XCD-swizzled col-fastest grid,
// double-buffered LDS + single barrier per K-step, source-chunk swizzle
// (chunk ^= (row>>1)&3) so ds_read_b128 frag reads are ~2-way conflict (free).
template<int TBM, int TBN>
__global__ __launch_bounds__(256) void k_mfma_gemm(
    const unsigned short* __restrict__ A,   // [MPAD][K] bf16
    const unsigned short* __restrict__ Bt,  // [FS][K] bf16
    unsigned short* __restrict__ Cbf,       // [M][FS] bf16 out
    int M, int K, int FS, int ncb)
{
  constexpr int MFR = TBM/32;   // 16x16 frags per wave (wave tile TBM/2 x TBN/2)
  constexpr int NFR = TBN/32;
  constexpr int ABYTES = TBM*64;  // bytes per K32 A-buffer
  constexpr int BBYTES = TBN*64;
  __shared__ unsigned short sA[2*TBM*32];
  __shared__ unsigned short sB[2*TBN*32];
  const int tid = threadIdx.x;
  const int wave = tid >> 6;
  const int lane = tid & 63;
  // bijective XCD swizzle (m204): contiguous wg-chunks per XCD
  const int nwg = gridDim.x;
  const int q = nwg >> 3, rmod = nwg & 7;
  const int xcd = blockIdx.x & 7, idx = blockIdx.x >> 3;
  const int wg = (xcd < rmod) ? (xcd*(q+1) + idx) : (rmod*(q+1) + (xcd - rmod)*q + idx);
  const int rowt = wg / ncb;
  const int colt = wg - rowt*ncb;
  const int row0 = rowt * TBM;
  const int col0 = colt * TBN;
  const int wr = (wave >> 1) * (TBM/2);
  const int wc = (wave & 1) * (TBN/2);
  f32x4 acc[MFR][NFR];
  #pragma unroll
  for (int i=0;i<MFR;i++)
    #pragma unroll
    for (int j=0;j<NFR;j++){ acc[i][j][0]=0.f; acc[i][j][1]=0.f; acc[i][j][2]=0.f; acc[i][j][3]=0.f; }

  // staging: lane (tid) owns LDS slot (row=tid>>2, chunk=tid&3); global source
  // chunk is XOR-swizzled so reads can de-conflict banks.
  const int arow = tid >> 2;
  const int achn = (tid & 3) ^ ((arow >> 1) & 3);
  const unsigned short* aSrc = A + (size_t)(row0 + arow)*K + achn*8;
  const unsigned short* bSrc = Bt + (size_t)(col0 + arow)*K + achn*8;
  char* ldsA = (char*)sA + wave*1024;
  char* ldsB = (char*)sB + wave*1024;

  const int NT = K >> 5;
  // prologue: stage tile 0 into buffer 0
  {
    #pragma unroll
    for (int h=0; h<TBM/64; h++) gload_lds16(aSrc + (size_t)h*64*K, ldsA + h*4096);
    #pragma unroll
    for (int h=0; h<TBN/64; h++) gload_lds16(bSrc + (size_t)h*64*K, ldsB + h*4096);
  }
  __syncthreads();
  int cur = 0;
  const int kch = lane >> 4;
  const int rlo = lane & 15;
  for (int t = 0; t < NT; ++t){
    if (t+1 < NT){
      int k0 = (t+1) << 5;
      int nb = cur ^ 1;
      #pragma unroll
      for (int h=0; h<TBM/64; h++) gload_lds16(aSrc + (size_t)h*64*K + k0, ldsA + nb*ABYTES + h*4096);
      #pragma unroll
      for (int h=0; h<TBN/64; h++) gload_lds16(bSrc + (size_t)h*64*K + k0, ldsB + nb*BBYTES + h*4096);
    }
    const unsigned short* bA = sA + cur*(TBM*32);
    const unsigned short* bB = sB + cur*(TBN*32);
    short8 af[MFR], bfr[NFR];
    #pragma unroll
    for (int m=0;m<MFR;m++){
      int r = wr + m*16 + rlo;
      af[m] = *(const short8*)(bA + r*32 + ((kch ^ ((r>>1)&3))<<3));
    }
    #pragma unroll
    for (int n=0;n<NFR;n++){
      int r = wc + n*16 + rlo;
      bfr[n] = *(const short8*)(bB + r*32 + ((kch ^ ((r>>1)&3))<<3));
    }
    #pragma unroll
    for (int m=0;m<MFR;m++)
      #pragma unroll
      for (int n=0;n<NFR;n++)
        acc[m][n] = __builtin_amdgcn_mfma_f32_16x16x32_bf16(af[m], bfr[n], acc[m][n], 0, 0, 0);
    __syncthreads();   // drains next-tile loads (vmcnt0) + this tile's lds reads
    cur ^= 1;
  }
  const int cr = (lane >> 4) * 4;
  const int cc = lane & 15;
  #pragma unroll
  for (int m=0;m<MFR;m++){
    #pragma unroll
    for (int n=0;n<NFR;n++){
      int col = col0 + wc + n*16 + cc;
      #pragma unroll
      for (int r=0;r<4;r++){
        int row = row0 + wr + m*16 + cr + r;
        if (row < M) Cbf[(size_t)row*FS + col] = f2bf(acc[m][n][r]);
      }
    }
  }
}

// ---------- per-node per-head attention halves (bf16 h, stride FS) ----------
__global__ void k_attprep(const unsigned short* __restrict__ h, const float* __restrict__ atts,
                          const float* __restrict__ attd,
                          float* __restrict__ a_s, float* __restrict__ a_d, int H, int C, int FS){
  int node = blockIdx.x, head = blockIdx.y;
  int lane = threadIdx.x;           // 64
  const unsigned short* hp = h + (size_t)node*FS + head*C;
  const float* sp = atts + head*C;
  const float* dp = attd + head*C;
  float ss = 0.f, sd = 0.f;
  for (int c = lane; c < C; c += 64){ float v = bf2f(hp[c]); ss += v*sp[c]; sd += v*dp[c]; }
  #pragma unroll
  for (int o = 32; o; o >>= 1){ ss += __shfl_down(ss, o); sd += __shfl_down(sd, o); }
  if (lane == 0){ a_s[node*H + head] = ss; a_d[node*H + head] = sd; }
}

// ---------- per-node softmax -> alphaT[h][E2] (one wave per node) ----------
__global__ void k_alpha(const float* __restrict__ a_s, const float* __restrict__ a_d,
                        const int* __restrict__ ptr, const int* __restrict__ csrc,
                        float* __restrict__ alphaT, int H, int LH){
  int node = blockIdx.x;
  int lane = threadIdx.x;   // 64
  int beg = ptr[node], deg = ptr[node+1] - beg;
  int items = deg << LH;    // deg*H
  int hh = lane & (H-1);    // constant per lane (64 % H == 0)
  float ad = a_d[node*H + hh];
  float mx = -INFINITY;
  for (int i = lane; i < items; i += 64){
    int e = i >> LH;
    int s = csrc[beg + e];
    float ev = a_s[s*H + hh] + ad;
    ev = ev > 0.f ? ev : 0.2f*ev;
    mx = fmaxf(mx, ev);
  }
  for (int o = H; o < 64; o <<= 1) mx = fmaxf(mx, __shfl_xor(mx, o));
  float den = 0.f;
  for (int i = lane; i < items; i += 64){
    int e = i >> LH;
    int s = csrc[beg + e];
    float ev = a_s[s*H + hh] + ad;
    ev = ev > 0.f ? ev : 0.2f*ev;
    den += __expf(ev - mx);
  }
  for (int o = H; o < 64; o <<= 1) den += __shfl_xor(den, o);
  float inv = 1.f / (den + 1e-16f);
  for (int i = lane; i < items; i += 64){
    int e = i >> LH;
    int s = csrc[beg + e];
    float ev = a_s[s*H + hh] + ad;
    ev = ev > 0.f ? ev : 0.2f*ev;
    alphaT[(size_t)hh*E2 + beg + e] = __expf(ev - mx) * inv;
  }
}

// ---------- weighted gather: grid (NN, H); block covers CS = L*8 channels ----------
template<int L>
__global__ __launch_bounds__(256) void k_gather2(
    const unsigned short* __restrict__ h, int FS,
    const float* __restrict__ alphaT,
    const int* __restrict__ ptr, const int* __restrict__ csrc,
    const float* __restrict__ bias, float* __restrict__ out,
    int F, int C, int outF)
{
  constexpr int NGRP = 256 / L;
  constexpr int CS = L * 8;
  const int node = blockIdx.x;
  const int head = blockIdx.y;
  const int colbase = head * C;
  const int beg = ptr[node], deg = ptr[node+1] - beg;
  __shared__ int ssrc[256];
  __shared__ float sal[256];
  __shared__ float red[NGRP * CS];   // 8 KB
  const int tid = threadIdx.x;
  const int grp = tid / L, li = tid % L;
  const int c0 = colbase + li*8;
  const float* aT = alphaT + (size_t)head*E2 + beg;
  float acc[8] = {0.f,0.f,0.f,0.f,0.f,0.f,0.f,0.f};
  for (int b0 = 0; b0 < deg; b0 += 256){
    int bn = min(256, deg - b0);
    if (tid < bn){ ssrc[tid] = csrc[beg + b0 + tid]; sal[tid] = aT[b0 + tid]; }
    __syncthreads();
    for (int e = grp; e < bn; e += NGRP){
      int s = ssrc[e];
      float al = sal[e];
      short8 v = *(const short8*)(h + (size_t)s*FS + c0);
      #pragma unroll
      for (int j=0;j<8;j++) acc[j] += bf2f((unsigned short)v[j]) * al;
    }
    __syncthreads();
  }
  #pragma unroll
  for (int j=0;j<8;j++) red[grp*CS + li*8 + j] = acc[j];
  __syncthreads();
  for (int c = tid; c < CS; c += 256){
    float s = 0.f;
    #pragma unroll
    for (int g=0; g<NGRP; g++) s += red[g*CS + c];
    int oc = colbase + c;
    if (oc < F) out[(size_t)node*outF + oc] = s + bias[oc];
  }
}

// ---------- GraphNorm stats / coefs / apply+ELU ----------
#define NSPLIT 16
__global__ void k_gnstats(const float* __restrict__ x, const int* __restrict__ gptr,
                          float* __restrict__ gsum, float* __restrict__ gsq, int F){
  int g = blockIdx.x, cc = blockIdx.y, sp = blockIdx.z;
  int c = cc*256 + threadIdx.x;
  if (c >= F) return;
  int beg = gptr[g], end = gptr[g+1];
  int n = end - beg;
  int per = (n + NSPLIT - 1) / NSPLIT;
  int nb = beg + sp*per, ne = min(end, nb + per);
  if (ne <= nb) return;
  float s = 0.f, q = 0.f;
  for (int i = nb; i < ne; i++){ float v = x[(size_t)i*F + c]; s += v; q += v*v; }
  atomicAdd(&gsum[g*F + c], s);
  atomicAdd(&gsq[g*F + c], q);
}

__global__ void k_coef(const float* __restrict__ gsum, const float* __restrict__ gsq, const int* __restrict__ gptr,
                       const float* __restrict__ w, const float* __restrict__ b, const float* __restrict__ ms,
                       float* __restrict__ cA, float* __restrict__ cB, int F){
  int i = blockIdx.x*256 + threadIdx.x;
  if (i >= NG*F) return;
  int g = i / F, c = i - g*F;
  float cntf = (float)(gptr[g+1] - gptr[g]);
  float m = gsum[i] / cntf;
  float s = ms[c];
  float ex2 = gsq[i] / cntf;
  float var = ex2 - 2.f*s*m*m + s*s*m*m;
  float inv = rsqrtf(var + 1e-5f);
  float wa = w[c]*inv;
  cA[i] = wa;
  cB[i] = b[c] - wa*m*s;
}

__global__ void k_applyelu(const float* __restrict__ x, const int* __restrict__ batch,
                           const float* __restrict__ cA, const float* __restrict__ cB,
                           unsigned short* __restrict__ obf, int F){
  size_t i = (size_t)blockIdx.x*256 + threadIdx.x;
  if (i >= (size_t)NN*F) return;
  int node = (int)(i / F);
  int c = (int)(i - (size_t)node*F);
  int g = batch[node];
  float y = cA[g*F + c]*x[i] + cB[g*F + c];
  y = y > 0.f ? y : expm1f(y);
  obf[i] = f2bf(y);
}

// ---------- orchestration ----------
extern "C" void kernel_launch(void* const* d_in, const int* in_sizes, int n_in,
                              void* d_out, int out_size, void* d_ws, size_t ws_size,
                              hipStream_t stream){
  (void)in_sizes; (void)n_in; (void)out_size; (void)ws_size;
  const float* x     = (const float*)d_in[0];
  const int*   ei    = (const int*)d_in[1];
  const int*   batch = (const int*)d_in[2];
  const float* W[4]  = {(const float*)d_in[3],  (const float*)d_in[7],  (const float*)d_in[11], (const float*)d_in[15]};
  const float* AS[4] = {(const float*)d_in[4],  (const float*)d_in[8],  (const float*)d_in[12], (const float*)d_in[16]};
  const float* AD[4] = {(const float*)d_in[5],  (const float*)d_in[9],  (const float*)d_in[13], (const float*)d_in[17]};
  const float* BI[4] = {(const float*)d_in[6],  (const float*)d_in[10], (const float*)d_in[14], (const float*)d_in[18]};
  const float* GW[3] = {(const float*)d_in[19], (const float*)d_in[22], (const float*)d_in[25]};
  const float* GB[3] = {(const float*)d_in[20], (const float*)d_in[23], (const float*)d_in[26]};
  const float* GA[3] = {(const float*)d_in[21], (const float*)d_in[24], (const float*)d_in[27]};

  float* ws   = (float*)d_ws;
  float* bufB = ws;                                  // [NN,1024] f32 (gather out / gnorm)
  float* a_s  = bufB + (size_t)NN*1024;              // [NN,4]
  float* a_d  = a_s + (size_t)NN*4;                  // [NN,4]
  float* gsum = a_d + (size_t)NN*4;                  // [NG,1024]
  float* gsq  = gsum + (size_t)NG*1024;              // [NG,1024]
  float* cA   = gsq  + (size_t)NG*1024;              // [NG,1024]
  float* cB   = cA   + (size_t)NG*1024;              // [NG,1024]
  float* alphaT = cB + (size_t)NG*1024;              // [4][E2]
  int* ptr  = (int*)(alphaT + (size_t)4*E2);         // [NN+1]
  int* fill = ptr + (NN + 8);                        // [NN+1]
  int* csrc = fill + (NN + 8);                       // [E2]
  int* gptr = csrc + E2;                             // [NG+1] (pad to 24)
  unsigned short* xbf = (unsigned short*)(gptr + 24);// [MPAD,64] bf16
  unsigned short* abf = xbf + (size_t)MPAD*64;       // [MPAD,1024] bf16 (layer inputs 1-3)
  unsigned short* hbf = abf + (size_t)MPAD*1024;     // [NN,1024] bf16 (GEMM out)
  unsigned short* Wt  = hbf + (size_t)NN*1024;       // [1024,1024] bf16 (per-layer W^T)

  // ---- CSR + graph boundaries (once per call) ----
  hipMemsetAsync(fill, 0, sizeof(int)*(NN+1), stream);
  k_gptr<<<1, 32, 0, stream>>>(batch, gptr);
  k_count<<<(E2+255)/256, 256, 0, stream>>>(ei, fill);
  k_scan<<<1, 256, 0, stream>>>(fill, ptr);
  k_copy<<<(NN+255)/256, 256, 0, stream>>>(ptr, fill);
  k_scatter<<<(E2+255)/256, 256, 0, stream>>>(ei, fill, csrc);
  k_xconv<<<(MPAD*64+255)/256, 256, 0, stream>>>(x, xbf);

  const int Kp[4]  = {64, 1024, 1024, 1024};
  const int Kr[4]  = {50, 1024, 1024, 1024};
  const int Np[4]  = {1024, 1024, 1024, 128};
  for (int li = 0; li < 4; ++li){
    int H = (li == 3) ? 1 : 4;
    int LH = (li == 3) ? 0 : 2;
    int C = (li == 3) ? 121 : 256;
    int F = H*C;
    int FS = Np[li];                       // padded h stride (1024 / 128)
    const unsigned short* Ain = (li == 0) ? xbf : abf;
    k_wconv<<<(Np[li]*Kp[li]+255)/256, 256, 0, stream>>>(W[li], Wt, Kr[li], F, Kp[li], Np[li]);
    if (li < 3){
      int ncb = Np[li]/128;                // 8
      int nwg = (MPAD/64) * ncb;           // 158*8 = 1264
      k_mfma_gemm<64,128><<<nwg, 256, 0, stream>>>(Ain, Wt, hbf, NN, Kp[li], FS, ncb);
    } else {
      int ncb = Np[li]/64;                 // 2
      int nwg = (MPAD/64) * ncb;           // 316
      k_mfma_gemm<64,64><<<nwg, 256, 0, stream>>>(Ain, Wt, hbf, NN, Kp[li], FS, ncb);
    }
    k_attprep<<<dim3(NN, H), 64, 0, stream>>>(hbf, AS[li], AD[li], a_s, a_d, H, C, FS);
    k_alpha<<<NN, 64, 0, stream>>>(a_s, a_d, ptr, csrc, alphaT, H, LH);
    float* gout = (li == 3) ? (float*)d_out : bufB;
    if (li < 3)
      k_gather2<32><<<dim3(NN, 4), 256, 0, stream>>>(hbf, FS, alphaT, ptr, csrc, BI[li], gout, F, C, F);
    else
      k_gather2<16><<<dim3(NN, 1), 256, 0, stream>>>(hbf, FS, alphaT, ptr, csrc, BI[li], gout, F, C, F);
    if (li < 3){
      hipMemsetAsync(gsum, 0, sizeof(float)*2*NG*1024, stream);
      k_gnstats<<<dim3(NG, (F+255)/256, NSPLIT), 256, 0, stream>>>(bufB, gptr, gsum, gsq, F);
      k_coef<<<(NG*F + 255)/256, 256, 0, stream>>>(gsum, gsq, gptr, GW[li], GB[li], GA[li], cA, cB, F);
      size_t tot = (size_t)NN*F;
      k_applyelu<<<(unsigned)((tot + 255)/256), 256, 0, stream>>>(bufB, batch, cA, cB, abf, F);
    }
  }
}

// Round 7
// 550.654 us; speedup vs baseline: 1.1064x; 1.0352x over previous
//
#include <hip/hip_runtime.h>
#include <math.h>

#define NN 10000
#define NE 160000
#define E2 (NE + NN)
#define NG 20
#define MPAD 10112   // 79 * 128

typedef __attribute__((ext_vector_type(8))) short short8;
typedef __attribute__((ext_vector_type(4))) float f32x4;

// ---------- helpers ----------
__device__ inline unsigned short f2bf(float f){
  unsigned u = __float_as_uint(f);
  unsigned r = u + 0x7FFFu + ((u >> 16) & 1u);
  return (unsigned short)(r >> 16);
}
__device__ inline float bf2f(unsigned short h){ return __uint_as_float(((unsigned)h) << 16); }

__device__ inline void gload_lds16(const void* g, void* l){
  __builtin_amdgcn_global_load_lds((const __attribute__((address_space(1))) void*)g,
                                   (__attribute__((address_space(3))) void*)l, 16, 0, 0);
}

// ---------- graph boundary (batch is sorted) ----------
__global__ void k_gptr(const int* __restrict__ batch, int* __restrict__ gptr){
  int g = threadIdx.x;
  if (g > NG) return;
  int lo = 0, hi = NN;
  while (lo < hi){ int mid = (lo+hi)>>1; if (batch[mid] < g) lo = mid+1; else hi = mid; }
  gptr[g] = lo;
}

// ---------- CSR build (by dst, self-loops appended) ----------
__global__ void k_count(const int* __restrict__ ei, int* __restrict__ cnt){
  int e = blockIdx.x*256 + threadIdx.x;
  if (e >= E2) return;
  int d = (e < NE) ? ei[NE + e] : (e - NE);
  atomicAdd(&cnt[d], 1);
}

__global__ void k_scan(const int* __restrict__ cnt, int* __restrict__ ptr){
  __shared__ int tpre[256];
  __shared__ int tsum[256];
  int tid = threadIdx.x;
  const int per = (NN + 255)/256;
  int base = tid*per;
  int s = 0;
  for (int i=0;i<per;i++){ int idx=base+i; if (idx<NN) s += cnt[idx]; }
  tsum[tid] = s;
  __syncthreads();
  if (tid == 0){
    int run = 0;
    for (int i=0;i<256;i++){ tpre[i]=run; run += tsum[i]; }
    ptr[NN] = run;
  }
  __syncthreads();
  int run = tpre[tid];
  for (int i=0;i<per;i++){ int idx=base+i; if (idx<NN){ ptr[idx]=run; run += cnt[idx]; } }
}

__global__ void k_copy(const int* __restrict__ src, int* __restrict__ dst){
  int i = blockIdx.x*256 + threadIdx.x;
  if (i < NN) dst[i] = src[i];
}

__global__ void k_scatter(const int* __restrict__ ei, int* __restrict__ fill, int* __restrict__ csrc){
  int e = blockIdx.x*256 + threadIdx.x;
  if (e >= E2) return;
  int s, d;
  if (e < NE){ s = ei[e]; d = ei[NE + e]; } else { s = d = e - NE; }
  int pos = atomicAdd(&fill[d], 1);
  csrc[pos] = s;
}

// ---------- conversions ----------
__global__ void k_xconv(const float* __restrict__ x, unsigned short* __restrict__ xbf){
  int i = blockIdx.x*256 + threadIdx.x;
  if (i >= MPAD*64) return;
  int r = i >> 6, c = i & 63;
  float v = (r < NN && c < 50) ? x[r*50 + c] : 0.f;
  xbf[i] = f2bf(v);
}

// W: [K][N] row-major f32 -> Wt: [Npad][Kpad] bf16 (transposed, zero-padded)
__global__ void k_wconv(const float* __restrict__ W, unsigned short* __restrict__ Wt,
                        int K, int N, int Kpad, int Npad){
  int i = blockIdx.x*256 + threadIdx.x;
  if (i >= Npad*Kpad) return;
  int nn = i / Kpad, kk = i - nn*Kpad;
  float v = (nn < N && kk < K) ? W[(size_t)kk*N + nn] : 0.f;
  Wt[i] = f2bf(v);
}

// ---------- bf16 MFMA GEMM: C[M,FS] = A[Mpad,K] x Bt[FS,K]^T ----------
// TBM x TBN tile, BK=32, 4 waves (2x2), XCD-swizzled grid, chunk-swizzled LDS,
// 2-deep pipeline with COUNTED vmcnt (T3+T4): tile t+2's loads stay in flight
// across the barriers; only tile t+1's L loads are awaited per iteration.
template<int TBM, int TBN>
__global__ __launch_bounds__(256) void k_mfma_gemm(
    const unsigned short* __restrict__ A,   // [MPAD][K] bf16
    const unsigned short* __restrict__ Bt,  // [FS][K] bf16
    unsigned short* __restrict__ Cbf,       // [M][FS] bf16 out
    int M, int K, int FS, int ncb)
{
  constexpr int MFR = TBM/32;
  constexpr int NFR = TBN/32;
  constexpr int ABYTES = TBM*64;  // bytes per K32 A-buffer
  constexpr int BBYTES = TBN*64;
  __shared__ unsigned short sA[2*TBM*32];
  __shared__ unsigned short sB[2*TBN*32];
  const int tid = threadIdx.x;
  const int wave = tid >> 6;
  const int lane = tid & 63;
  // bijective XCD swizzle (m204)
  const int nwg = gridDim.x;
  const int q = nwg >> 3, rmod = nwg & 7;
  const int xcd = blockIdx.x & 7, idx = blockIdx.x >> 3;
  const int wg = (xcd < rmod) ? (xcd*(q+1) + idx) : (rmod*(q+1) + (xcd - rmod)*q + idx);
  const int rowt = wg / ncb;
  const int colt = wg - rowt*ncb;
  const int row0 = rowt * TBM;
  const int col0 = colt * TBN;
  const int wr = (wave >> 1) * (TBM/2);
  const int wc = (wave & 1) * (TBN/2);
  f32x4 acc[MFR][NFR];
  #pragma unroll
  for (int i=0;i<MFR;i++)
    #pragma unroll
    for (int j=0;j<NFR;j++){ acc[i][j][0]=0.f; acc[i][j][1]=0.f; acc[i][j][2]=0.f; acc[i][j][3]=0.f; }

  // staging: LDS dest linear (row=tid>>2, chunk=tid&3); global source chunk
  // XOR-swizzled so ds_read frag fetches are bank-spread (both-sides swizzle).
  const int arow = tid >> 2;
  const int achn = (tid & 3) ^ ((arow >> 1) & 3);
  const unsigned short* aSrc = A + (size_t)(row0 + arow)*K + achn*8;
  const unsigned short* bSrc = Bt + (size_t)(col0 + arow)*K + achn*8;
  char* ldsA = (char*)sA + wave*1024;
  char* ldsB = (char*)sB + wave*1024;

  auto STAGE = [&](int k0, int buf){
    #pragma unroll
    for (int h=0; h<TBM/64; h++) gload_lds16(aSrc + (size_t)h*64*K + k0, ldsA + buf*ABYTES + h*4096);
    #pragma unroll
    for (int h=0; h<TBN/64; h++) gload_lds16(bSrc + (size_t)h*64*K + k0, ldsB + buf*BBYTES + h*4096);
  };

  const int NT = K >> 5;
  const int kch = lane >> 4;
  const int rlo = lane & 15;

  // prologue: stage tiles 0 and 1; wait tile 0 (tile 1's L loads stay out)
  STAGE(0, 0);
  if (NT > 1) STAGE(32, 1);
  if constexpr (TBM+TBN == 256) asm volatile("s_waitcnt vmcnt(4)" ::: "memory");
  else                          asm volatile("s_waitcnt vmcnt(2)" ::: "memory");
  __builtin_amdgcn_sched_barrier(0);
  __builtin_amdgcn_s_barrier();

  int cur = 0;
  for (int t = 0; t < NT; ++t){
    // frags from buf[cur]
    const unsigned short* bA = sA + cur*(TBM*32);
    const unsigned short* bB = sB + cur*(TBN*32);
    short8 af[MFR], bfr[NFR];
    #pragma unroll
    for (int m=0;m<MFR;m++){
      int r = wr + m*16 + rlo;
      af[m] = *(const short8*)(bA + r*32 + ((kch ^ ((r>>1)&3))<<3));
    }
    #pragma unroll
    for (int n=0;n<NFR;n++){
      int r = wc + n*16 + rlo;
      bfr[n] = *(const short8*)(bB + r*32 + ((kch ^ ((r>>1)&3))<<3));
    }
    asm volatile("s_waitcnt lgkmcnt(0)" ::: "memory");
    __builtin_amdgcn_sched_barrier(0);
    __builtin_amdgcn_s_barrier();          // all waves done reading buf[cur]
    if (t+2 < NT) STAGE((t+2) << 5, cur);  // overwrite cur; awaited at t+2
    #pragma unroll
    for (int m=0;m<MFR;m++)
      #pragma unroll
      for (int n=0;n<NFR;n++)
        acc[m][n] = __builtin_amdgcn_mfma_f32_16x16x32_bf16(af[m], bfr[n], acc[m][n], 0, 0, 0);
    if (t+1 < NT){
      if (t+2 < NT){
        if constexpr (TBM+TBN == 256) asm volatile("s_waitcnt vmcnt(4)" ::: "memory");
        else                          asm volatile("s_waitcnt vmcnt(2)" ::: "memory");
      } else {
        asm volatile("s_waitcnt vmcnt(0)" ::: "memory");
      }
      __builtin_amdgcn_sched_barrier(0);
      __builtin_amdgcn_s_barrier();        // buf[cur^1] (tile t+1) visible to all
    }
    cur ^= 1;
  }
  const int cr = (lane >> 4) * 4;
  const int cc = lane & 15;
  #pragma unroll
  for (int m=0;m<MFR;m++){
    #pragma unroll
    for (int n=0;n<NFR;n++){
      int col = col0 + wc + n*16 + cc;
      #pragma unroll
      for (int r=0;r<4;r++){
        int row = row0 + wr + m*16 + cr + r;
        if (row < M) Cbf[(size_t)row*FS + col] = f2bf(acc[m][n][r]);
      }
    }
  }
}

// ---------- per-node per-head attention halves (bf16 h, stride FS) ----------
__global__ void k_attprep(const unsigned short* __restrict__ h, const float* __restrict__ atts,
                          const float* __restrict__ attd,
                          float* __restrict__ a_s, float* __restrict__ a_d, int H, int C, int FS){
  int node = blockIdx.x, head = blockIdx.y;
  int lane = threadIdx.x;           // 64
  const unsigned short* hp = h + (size_t)node*FS + head*C;
  const float* sp = atts + head*C;
  const float* dp = attd + head*C;
  float ss = 0.f, sd = 0.f;
  for (int c = lane; c < C; c += 64){ float v = bf2f(hp[c]); ss += v*sp[c]; sd += v*dp[c]; }
  #pragma unroll
  for (int o = 32; o; o >>= 1){ ss += __shfl_down(ss, o); sd += __shfl_down(sd, o); }
  if (lane == 0){ a_s[node*H + head] = ss; a_d[node*H + head] = sd; }
}

// ---------- per-node softmax -> alphaT[h][E2] (one wave per node) ----------
__global__ void k_alpha(const float* __restrict__ a_s, const float* __restrict__ a_d,
                        const int* __restrict__ ptr, const int* __restrict__ csrc,
                        float* __restrict__ alphaT, int H, int LH){
  int node = blockIdx.x;
  int lane = threadIdx.x;   // 64
  int beg = ptr[node], deg = ptr[node+1] - beg;
  int items = deg << LH;    // deg*H
  int hh = lane & (H-1);    // constant per lane (64 % H == 0)
  float ad = a_d[node*H + hh];
  float mx = -INFINITY;
  for (int i = lane; i < items; i += 64){
    int e = i >> LH;
    int s = csrc[beg + e];
    float ev = a_s[s*H + hh] + ad;
    ev = ev > 0.f ? ev : 0.2f*ev;
    mx = fmaxf(mx, ev);
  }
  for (int o = H; o < 64; o <<= 1) mx = fmaxf(mx, __shfl_xor(mx, o));
  float den = 0.f;
  for (int i = lane; i < items; i += 64){
    int e = i >> LH;
    int s = csrc[beg + e];
    float ev = a_s[s*H + hh] + ad;
    ev = ev > 0.f ? ev : 0.2f*ev;
    den += __expf(ev - mx);
  }
  for (int o = H; o < 64; o <<= 1) den += __shfl_xor(den, o);
  float inv = 1.f / (den + 1e-16f);
  for (int i = lane; i < items; i += 64){
    int e = i >> LH;
    int s = csrc[beg + e];
    float ev = a_s[s*H + hh] + ad;
    ev = ev > 0.f ? ev : 0.2f*ev;
    alphaT[(size_t)hh*E2 + beg + e] = __expf(ev - mx) * inv;
  }
}

// ---------- weighted gather: grid (NN, H); block covers CS = L*8 channels ----------
template<int L>
__global__ __launch_bounds__(256) void k_gather2(
    const unsigned short* __restrict__ h, int FS,
    const float* __restrict__ alphaT,
    const int* __restrict__ ptr, const int* __restrict__ csrc,
    const float* __restrict__ bias, float* __restrict__ out,
    int F, int C, int outF)
{
  constexpr int NGRP = 256 / L;
  constexpr int CS = L * 8;
  const int node = blockIdx.x;
  const int head = blockIdx.y;
  const int colbase = head * C;
  const int beg = ptr[node], deg = ptr[node+1] - beg;
  __shared__ int ssrc[256];
  __shared__ float sal[256];
  __shared__ float red[NGRP * CS];   // 8 KB
  const int tid = threadIdx.x;
  const int grp = tid / L, li = tid % L;
  const int c0 = colbase + li*8;
  const float* aT = alphaT + (size_t)head*E2 + beg;
  float acc[8] = {0.f,0.f,0.f,0.f,0.f,0.f,0.f,0.f};
  for (int b0 = 0; b0 < deg; b0 += 256){
    int bn = min(256, deg - b0);
    if (tid < bn){ ssrc[tid] = csrc[beg + b0 + tid]; sal[tid] = aT[b0 + tid]; }
    __syncthreads();
    for (int e = grp; e < bn; e += NGRP){
      int s = ssrc[e];
      float al = sal[e];
      short8 v = *(const short8*)(h + (size_t)s*FS + c0);
      #pragma unroll
      for (int j=0;j<8;j++) acc[j] += bf2f((unsigned short)v[j]) * al;
    }
    __syncthreads();
  }
  #pragma unroll
  for (int j=0;j<8;j++) red[grp*CS + li*8 + j] = acc[j];
  __syncthreads();
  for (int c = tid; c < CS; c += 256){
    float s = 0.f;
    #pragma unroll
    for (int g=0; g<NGRP; g++) s += red[g*CS + c];
    int oc = colbase + c;
    if (oc < F) out[(size_t)node*outF + oc] = s + bias[oc];
  }
}

// ---------- GraphNorm stats / coefs / apply+ELU ----------
#define NSPLIT 16
__global__ void k_gnstats(const float* __restrict__ x, const int* __restrict__ gptr,
                          float* __restrict__ gsum, float* __restrict__ gsq, int F){
  int g = blockIdx.x, cc = blockIdx.y, sp = blockIdx.z;
  int c = cc*256 + threadIdx.x;
  if (c >= F) return;
  int beg = gptr[g], end = gptr[g+1];
  int n = end - beg;
  int per = (n + NSPLIT - 1) / NSPLIT;
  int nb = beg + sp*per, ne = min(end, nb + per);
  if (ne <= nb) return;
  float s = 0.f, q = 0.f;
  for (int i = nb; i < ne; i++){ float v = x[(size_t)i*F + c]; s += v; q += v*v; }
  atomicAdd(&gsum[g*F + c], s);
  atomicAdd(&gsq[g*F + c], q);
}

__global__ void k_coef(const float* __restrict__ gsum, const float* __restrict__ gsq, const int* __restrict__ gptr,
                       const float* __restrict__ w, const float* __restrict__ b, const float* __restrict__ ms,
                       float* __restrict__ cA, float* __restrict__ cB, int F){
  int i = blockIdx.x*256 + threadIdx.x;
  if (i >= NG*F) return;
  int g = i / F, c = i - g*F;
  float cntf = (float)(gptr[g+1] - gptr[g]);
  float m = gsum[i] / cntf;
  float s = ms[c];
  float ex2 = gsq[i] / cntf;
  float var = ex2 - 2.f*s*m*m + s*s*m*m;
  float inv = rsqrtf(var + 1e-5f);
  float wa = w[c]*inv;
  cA[i] = wa;
  cB[i] = b[c] - wa*m*s;
}

__global__ void k_applyelu(const float* __restrict__ x, const int* __restrict__ batch,
                           const float* __restrict__ cA, const float* __restrict__ cB,
                           unsigned short* __restrict__ obf, int F){
  size_t i = (size_t)blockIdx.x*256 + threadIdx.x;
  if (i >= (size_t)NN*F) return;
  int node = (int)(i / F);
  int c = (int)(i - (size_t)node*F);
  int g = batch[node];
  float y = cA[g*F + c]*x[i] + cB[g*F + c];
  y = y > 0.f ? y : expm1f(y);
  obf[i] = f2bf(y);
}

// ---------- orchestration ----------
extern "C" void kernel_launch(void* const* d_in, const int* in_sizes, int n_in,
                              void* d_out, int out_size, void* d_ws, size_t ws_size,
                              hipStream_t stream){
  (void)in_sizes; (void)n_in; (void)out_size; (void)ws_size;
  const float* x     = (const float*)d_in[0];
  const int*   ei    = (const int*)d_in[1];
  const int*   batch = (const int*)d_in[2];
  const float* W[4]  = {(const float*)d_in[3],  (const float*)d_in[7],  (const float*)d_in[11], (const float*)d_in[15]};
  const float* AS[4] = {(const float*)d_in[4],  (const float*)d_in[8],  (const float*)d_in[12], (const float*)d_in[16]};
  const float* AD[4] = {(const float*)d_in[5],  (const float*)d_in[9],  (const float*)d_in[13], (const float*)d_in[17]};
  const float* BI[4] = {(const float*)d_in[6],  (const float*)d_in[10], (const float*)d_in[14], (const float*)d_in[18]};
  const float* GW[3] = {(const float*)d_in[19], (const float*)d_in[22], (const float*)d_in[25]};
  const float* GB[3] = {(const float*)d_in[20], (const float*)d_in[23], (const float*)d_in[26]};
  const float* GA[3] = {(const float*)d_in[21], (const float*)d_in[24], (const float*)d_in[27]};

  float* ws   = (float*)d_ws;
  float* bufB = ws;                                  // [NN,1024] f32 (gather out / gnorm)
  float* a_s  = bufB + (size_t)NN*1024;              // [NN,4]
  float* a_d  = a_s + (size_t)NN*4;                  // [NN,4]
  float* gsum = a_d + (size_t)NN*4;                  // [NG,1024]
  float* gsq  = gsum + (size_t)NG*1024;              // [NG,1024]
  float* cA   = gsq  + (size_t)NG*1024;              // [NG,1024]
  float* cB   = cA   + (size_t)NG*1024;              // [NG,1024]
  float* alphaT = cB + (size_t)NG*1024;              // [4][E2]
  int* ptr  = (int*)(alphaT + (size_t)4*E2);         // [NN+1]
  int* fill = ptr + (NN + 8);                        // [NN+1]
  int* csrc = fill + (NN + 8);                       // [E2]
  int* gptr = csrc + E2;                             // [NG+1] (pad to 24)
  unsigned short* xbf = (unsigned short*)(gptr + 24);// [MPAD,64] bf16
  unsigned short* abf = xbf + (size_t)MPAD*64;       // [MPAD,1024] bf16 (layer inputs 1-3)
  unsigned short* hbf = abf + (size_t)MPAD*1024;     // [NN,1024] bf16 (GEMM out)
  unsigned short* Wt  = hbf + (size_t)NN*1024;       // [1024,1024] bf16 (per-layer W^T)

  // ---- CSR + graph boundaries (once per call) ----
  hipMemsetAsync(fill, 0, sizeof(int)*(NN+1), stream);
  k_gptr<<<1, 32, 0, stream>>>(batch, gptr);
  k_count<<<(E2+255)/256, 256, 0, stream>>>(ei, fill);
  k_scan<<<1, 256, 0, stream>>>(fill, ptr);
  k_copy<<<(NN+255)/256, 256, 0, stream>>>(ptr, fill);
  k_scatter<<<(E2+255)/256, 256, 0, stream>>>(ei, fill, csrc);
  k_xconv<<<(MPAD*64+255)/256, 256, 0, stream>>>(x, xbf);

  const int Kp[4]  = {64, 1024, 1024, 1024};
  const int Kr[4]  = {50, 1024, 1024, 1024};
  const int Np[4]  = {1024, 1024, 1024, 128};
  for (int li = 0; li < 4; ++li){
    int H = (li == 3) ? 1 : 4;
    int LH = (li == 3) ? 0 : 2;
    int C = (li == 3) ? 121 : 256;
    int F = H*C;
    int FS = Np[li];                       // padded h stride (1024 / 128)
    const unsigned short* Ain = (li == 0) ? xbf : abf;
    k_wconv<<<(Np[li]*Kp[li]+255)/256, 256, 0, stream>>>(W[li], Wt, Kr[li], F, Kp[li], Np[li]);
    if (li < 3){
      int ncb = Np[li]/128;                // 8
      int nwg = (MPAD/128) * ncb;          // 79*8 = 632
      k_mfma_gemm<128,128><<<nwg, 256, 0, stream>>>(Ain, Wt, hbf, NN, Kp[li], FS, ncb);
    } else {
      int ncb = Np[li]/64;                 // 2
      int nwg = (MPAD/64) * ncb;           // 316
      k_mfma_gemm<64,64><<<nwg, 256, 0, stream>>>(Ain, Wt, hbf, NN, Kp[li], FS, ncb);
    }
    k_attprep<<<dim3(NN, H), 64, 0, stream>>>(hbf, AS[li], AD[li], a_s, a_d, H, C, FS);
    k_alpha<<<NN, 64, 0, stream>>>(a_s, a_d, ptr, csrc, alphaT, H, LH);
    float* gout = (li == 3) ? (float*)d_out : bufB;
    if (li < 3)
      k_gather2<32><<<dim3(NN, 4), 256, 0, stream>>>(hbf, FS, alphaT, ptr, csrc, BI[li], gout, F, C, F);
    else
      k_gather2<16><<<dim3(NN, 1), 256, 0, stream>>>(hbf, FS, alphaT, ptr, csrc, BI[li], gout, F, C, F);
    if (li < 3){
      hipMemsetAsync(gsum, 0, sizeof(float)*2*NG*1024, stream);
      k_gnstats<<<dim3(NG, (F+255)/256, NSPLIT), 256, 0, stream>>>(bufB, gptr, gsum, gsq, F);
      k_coef<<<(NG*F + 255)/256, 256, 0, stream>>>(gsum, gsq, gptr, GW[li], GB[li], GA[li], cA, cB, F);
      size_t tot = (size_t)NN*F;
      k_applyelu<<<(unsigned)((tot + 255)/256), 256, 0, stream>>>(bufB, batch, cA, cB, abf, F);
    }
  }
}